// Round 11
// baseline (389.071 us; speedup 1.0000x reference)
//
#include <hip/hip_runtime.h>

// GatedRecurrentCell: B=8 S=2048 D=512 I=2048. M=B*S=16384, N2=2*I=4096, K=D=512.
// R11: gate math moved into the GEMM epilogue REGISTER-ONLY (the R0-R9 fused
// epilogue's cost was the LDS C-stage + barriers + serial scan, NOT gate math
// — proven by R10's split: 146 -> 82us). Frag-native (pa,pi) pairs live in
// ADJACENT LANES (n = ...+lrow): bias -> shfl_xor(1) -> both lanes compute
// (a,c) in f32 -> even lane stores a, odd stores c (same f16x4 store as R10).
// No LDS, no barriers. Downstream passes become pure-fma:
//   gate_agg: AC -> 32-chunk (A,H), no transcendentals.
//   scan_out: AC + carry -> out, h = a*h + c replay.
// a,c now derived from f32 pa/pi (more precise than R10's f16 round-trip);
// agg and replay consume identical f16 (a,c) -> consistent.
// ws: [0,16Mi) x_f16 | [16,20Mi) W_f16 | [20Mi,+128Mi) AC f16 | +8Mi agg | +4Mi carry

#define LOG2_3 1.5849625007211562f

typedef _Float16 f16x8 __attribute__((ext_vector_type(8)));
typedef _Float16 f16x4 __attribute__((ext_vector_type(4)));
typedef _Float16 f16x2 __attribute__((ext_vector_type(2)));
typedef float f32x4 __attribute__((ext_vector_type(4)));

__device__ __forceinline__ float sigmoid_fast(float v) {
  return __fdividef(1.0f, 1.0f + __expf(-v));
}

__device__ __forceinline__ void async_copy16(void* lds, const void* gp) {
  __builtin_amdgcn_global_load_lds((__attribute__((address_space(1))) void*)gp,
                                   (__attribute__((address_space(3))) void*)lds,
                                   16, 0, 0);
}

// x -> xh (plain). Wa/Wi -> wh with row interleave: wh row 2i = Wa_i, 2i+1 = Wi_i.
__global__ __launch_bounds__(256) void cvt_all(const float* __restrict__ x,
                                               const float* __restrict__ Wa,
                                               const float* __restrict__ Wi,
                                               _Float16* __restrict__ xh,
                                               _Float16* __restrict__ wh) {
  int idx = blockIdx.x * 256 + threadIdx.x;
  const float* src;
  _Float16* dst;
  int off, doff;
  if (idx < 2097152) {
    src = x; dst = xh; off = idx; doff = idx;
  } else if (idx < 2097152 + 262144) {
    src = Wa; dst = wh; off = idx - 2097152;
    doff = off + ((off >> 7) << 7);          // (2i)*128 + k4
  } else {
    src = Wi; dst = wh; off = idx - 2359296;
    doff = off + ((off >> 7) << 7) + 128;    // (2i+1)*128 + k4
  }
  float4 v = ((const float4*)src)[off];
  f16x4 h;
  h[0] = (_Float16)v.x;
  h[1] = (_Float16)v.y;
  h[2] = (_Float16)v.z;
  h[3] = (_Float16)v.w;
  ((f16x4*)dst)[doff] = h;
}

__device__ __forceinline__ void gate_ac(float pa, float pi, float alpha, float& a, float& c) {
  float rg = sigmoid_fast(pa);
  a = alpha * exp2f(-LOG2_3 * rg);
  float ig = sigmoid_fast(pi);
  float m = fmaxf(1.0f - a * a, 1e-8f);
  c = (m * __frsqrt_rn(m)) * (ig * pi);  // sqrt(m) = m * rsqrt(m)
}

// GEMM 256x256 tile, 8 waves, K-loop identical to R9/R10 (2-phase, XOR swizzle).
// Epilogue: bias -> lane-pair shfl_xor -> gate_ac in f32 -> frag-native f16x4
// stores (even lrow lane stores a, odd stores c). No LDS, no barriers.
// AC layout == R10 PP layout: AC[(by*16+bx)<<16 | wave*8192 | i*1024 | j*256 |
// lane*4 | rr]; m = by*256+(wave&1)*128+i*16+(lane>>4)*4+rr,
// n = bx*256+(wave>>1)*64+j*16+(lane&15). Even n col = a, odd n col = c.
__global__ __launch_bounds__(512) void gemm_ac(const _Float16* __restrict__ Ah,
                                               const _Float16* __restrict__ Wh,
                                               const float* __restrict__ ba,
                                               const float* __restrict__ bi,
                                               const float* __restrict__ gate,
                                               _Float16* __restrict__ AC) {
  constexpr int K = 512;
  __shared__ __align__(16) _Float16 smem[32768];  // 64 KiB: 2 x 32KB K-buffers
  const int t = threadIdx.x;
  const int bx = blockIdx.x;  // 0..15 (n)
  const int by = blockIdx.y;  // 0..63 (m)
  const int mBase = by * 256;
  const int nBase = bx * 256;
  const int r = t >> 2;                      // staged row 0..127 (+128 for 2nd)
  const int p = t & 3;                       // physical 16B slot
  const int lsw = p ^ ((r >> 1) & 3);        // pre-swizzled source slot
  const _Float16* gA0 = Ah + (size_t)(mBase + r) * K + lsw * 8;
  const _Float16* gB0 = Wh + (size_t)(nBase + r) * K + lsw * 8;
  const int ldst = r * 32 + p * 8;           // byte off == t*16 (linear)

  const int lane = t & 63;
  const int wave = t >> 6;                   // 0..7
  const int wm = (wave & 1) * 128;
  const int wn = (wave >> 1) * 64;
  const int lrow = lane & 15;
  const int quad = lane >> 4;
  const int xq = quad ^ ((lrow >> 1) & 3);   // read-side swizzle

  f32x4 acc[8][4];
#pragma unroll
  for (int i = 0; i < 8; ++i)
#pragma unroll
    for (int j = 0; j < 4; ++j)
      acc[i][j] = (f32x4)0.0f;

  _Float16* b0 = smem;
  _Float16* b1 = smem + 16384;

  auto STAGE = [&](int tt, _Float16* bb) {
    const int ko = tt * 32;
    async_copy16(bb + ldst, gA0 + ko);                            // A rows 0-127
    async_copy16(bb + 4096 + ldst, gA0 + (size_t)128 * K + ko);   // A rows 128-255
    async_copy16(bb + 8192 + ldst, gB0 + ko);                     // B rows 0-127
    async_copy16(bb + 12288 + ldst, gB0 + (size_t)128 * K + ko);  // B rows 128-255
  };

  STAGE(0, b0);
  __syncthreads();

#pragma unroll
  for (int kt = 0; kt < 16; ++kt) {
    _Float16* cur = (kt & 1) ? b1 : b0;
    _Float16* nxt = (kt & 1) ? b0 : b1;
    if (kt < 15) STAGE(kt + 1, nxt);  // issue BEFORE compute; lands by next barrier
    f16x8 af[8], bf[4];
#pragma unroll
    for (int i = 0; i < 8; ++i)
      af[i] = *(const f16x8*)(cur + (wm + i * 16 + lrow) * 32 + xq * 8);
#pragma unroll
    for (int j = 0; j < 4; ++j)
      bf[j] = *(const f16x8*)(cur + 8192 + (wn + j * 16 + lrow) * 32 + xq * 8);
#pragma unroll
    for (int i = 0; i < 8; ++i)
#pragma unroll
      for (int j = 0; j < 4; ++j)
        acc[i][j] = __builtin_amdgcn_mfma_f32_16x16x32_f16(af[i], bf[j], acc[i][j], 0, 0, 0);
    __syncthreads();  // single barrier/K-step
  }

  // bias + alpha: even n col -> ba, odd -> bi; alpha per column-pair (i-unit)
  const int odd = lane & 1;
  float bias[4], alpha[4];
#pragma unroll
  for (int j = 0; j < 4; ++j) {
    const int n = nBase + wn + j * 16 + lrow;
    bias[j] = odd ? bi[n >> 1] : ba[n >> 1];
    alpha[j] = sigmoid_fast(gate[n >> 1]);  // n>>1 identical for the pair
  }

  // register-only gate epilogue: pair-exchange via shfl_xor(1), gate in f32,
  // even lane stores a, odd stores c; frag-native f16x4 stores (8B/lane).
  _Float16* pp = AC + (((size_t)by * 16 + bx) << 16) + wave * 8192 + lane * 4;
#pragma unroll
  for (int i = 0; i < 8; ++i)
#pragma unroll
    for (int j = 0; j < 4; ++j) {
      f16x4 st;
#pragma unroll
      for (int rr = 0; rr < 4; ++rr) {
        float own = acc[i][j][rr] + bias[j];
        float par = __shfl_xor(own, 1);
        float pa = odd ? par : own;
        float pi = odd ? own : par;
        float a, c;
        gate_ac(pa, pi, alpha[j], a, c);
        st[rr] = (_Float16)(odd ? c : a);
      }
      *(f16x4*)(pp + i * 1024 + j * 256) = st;
    }
}

// AC -> 32-step chunk aggregates (A = prod a, H = fold a*H+c). Pure fma.
// One f16x8 load = 4 rows of (a,c) for column-pair tt.
__global__ __launch_bounds__(256) void gate_agg(const _Float16* __restrict__ AC,
                                                float2* __restrict__ agg) {
  const int tt = blockIdx.x * 256 + threadIdx.x;  // 0..2047
  const int ch = blockIdx.y;                      // 0..63
  const int b = blockIdx.z;                       // 0..7
  const int n = tt * 2;
  const int bx = n >> 8;
  const int nl = n & 255;
  const int wn_idx = nl >> 6;
  const int j = (nl >> 4) & 3;
  const int lrow = nl & 15;                       // even
  const int by = b * 8 + (ch >> 3);
  const int c8 = ch & 7;
  const int wm_bit = c8 >> 2;
  const _Float16* base = AC + (((size_t)by * 16 + bx) << 16) +
                         (wm_bit + 2 * wn_idx) * 8192 + j * 256 + lrow * 4;
  f16x8 v[8];
#pragma unroll
  for (int u = 0; u < 8; ++u) {
    const int i = (c8 * 2 + (u >> 2)) & 7;  // s = (u>>2)*16 + (u&3)*4 + rr
    v[u] = *(const f16x8*)(base + i * 1024 + (u & 3) * 64);
  }
  float A = 1.0f, H = 0.0f;
#pragma unroll
  for (int u = 0; u < 8; ++u)
#pragma unroll
    for (int rr = 0; rr < 4; ++rr) {
      float a = (float)v[u][rr];
      float c = (float)v[u][4 + rr];
      A *= a;
      H = fmaf(a, H, c);
    }
  agg[((size_t)(b * 64 + ch)) * 2048 + tt] = make_float2(A, H);
}

__global__ __launch_bounds__(64) void scan_pass2(const float2* __restrict__ agg,
                                                 float* __restrict__ carry) {
  const int i = blockIdx.x * 64 + threadIdx.x;  // grid.x=32 -> 0..2047
  const int b = blockIdx.y;
  float h = 0.0f;
  for (int c8 = 0; c8 < 8; ++c8) {
    float2 aH[8];
#pragma unroll
    for (int u = 0; u < 8; ++u)
      aH[u] = agg[((size_t)(b * 64 + c8 * 8 + u)) * 2048 + i];
#pragma unroll
    for (int u = 0; u < 8; ++u) {
      carry[((size_t)(b * 64 + c8 * 8 + u)) * 2048 + i] = h;
      h = fmaf(aH[u].x, h, aH[u].y);
    }
  }
}

// Pure fma replay from AC: h = a*h + c. Same f16 (a,c) as gate_agg used.
__global__ __launch_bounds__(256) void scan_out(const _Float16* __restrict__ AC,
                                                const float* __restrict__ carry,
                                                float* __restrict__ out) {
  const int tt = blockIdx.x * 256 + threadIdx.x;  // 0..2047
  const int ch = blockIdx.y;                      // 0..63
  const int b = blockIdx.z;                       // 0..7
  float h = carry[((size_t)(b * 64 + ch)) * 2048 + tt];
  const int n = tt * 2;
  const int bx = n >> 8;
  const int nl = n & 255;
  const int wn_idx = nl >> 6;
  const int j = (nl >> 4) & 3;
  const int lrow = nl & 15;
  const int by = b * 8 + (ch >> 3);
  const int c8 = ch & 7;
  const int wm_bit = c8 >> 2;
  const _Float16* base = AC + (((size_t)by * 16 + bx) << 16) +
                         (wm_bit + 2 * wn_idx) * 8192 + j * 256 + lrow * 4;
  f16x8 v[8];
#pragma unroll
  for (int u = 0; u < 8; ++u) {
    const int i = (c8 * 2 + (u >> 2)) & 7;
    v[u] = *(const f16x8*)(base + i * 1024 + (u & 3) * 64);
  }
  float* orow = out + ((size_t)(b * 2048 + ch * 32)) * 2048 + tt;
#pragma unroll
  for (int u = 0; u < 8; ++u)
#pragma unroll
    for (int rr = 0; rr < 4; ++rr) {
      h = fmaf((float)v[u][rr], h, (float)v[u][4 + rr]);
      __builtin_nontemporal_store(h, orow);
      orow += 2048;
    }
}

extern "C" void kernel_launch(void* const* d_in, const int* in_sizes, int n_in,
                              void* d_out, int out_size, void* d_ws, size_t ws_size,
                              hipStream_t stream) {
  const float* x = (const float*)d_in[0];
  const float* Wa = (const float*)d_in[1];
  const float* ba = (const float*)d_in[2];
  const float* Wi = (const float*)d_in[3];
  const float* bi = (const float*)d_in[4];
  const float* gate = (const float*)d_in[5];
  float* out = (float*)d_out;

  char* ws = (char*)d_ws;
  _Float16* xh = (_Float16*)ws;               // 16 MiB
  _Float16* wh = (_Float16*)(ws + 16777216);  // 4 MiB (interleaved Wa/Wi)
  const size_t MN2 = (size_t)16384 * 4096;
  _Float16* AC = (_Float16*)(ws + 20971520);  // 128 MiB (a,c) frag-native
  float2* agg = (float2*)(ws + 20971520 + MN2 * 2);            // 8 MiB
  float* carry = (float*)(ws + 20971520 + MN2 * 2 + 8388608);  // 4 MiB

  cvt_all<<<10240, 256, 0, stream>>>(x, Wa, Wi, xh, wh);
  gemm_ac<<<dim3(16, 64), 512, 0, stream>>>(xh, wh, ba, bi, gate, AC);
  gate_agg<<<dim3(8, 64, 8), 256, 0, stream>>>(AC, agg);
  scan_pass2<<<dim3(32, 8), 64, 0, stream>>>(agg, carry);
  scan_out<<<dim3(8, 64, 8), 256, 0, stream>>>(AC, carry, out);
}

// Round 13
// 332.456 us; speedup vs baseline: 1.1703x; 1.1703x over previous
//
#include <hip/hip_runtime.h>

// GatedRecurrentCell: B=8 S=2048 D=512 I=2048. M=B*S=16384, N2=2*I=4096, K=D=512.
// R13 == R12 resubmitted verbatim (R12 died at container acquire — infra; the
// kernel never ran; full layout audit found no hazard).
// R12: zero-shfl register gate epilogue via PAIRED-COLUMN W layout. R11 showed
// the shfl_xor pair-exchange (128 ds_permute+lgkm waits at 1.3 blocks/CU) cost
// ~167us. Fix: permute wh rows so a unit's (pa,pi) land in the SAME LANE,
// adjacent j-fragments: per 64-col group, cols [0:16)=pa u0-15, [16:32)=pi
// u0-15, [32:48)=pa u16-31, [48:64)=pi u16-31. Wa_i -> wh row 2*(i&~15)+(i&15),
// Wi_i -> +16. Epilogue: 64 lane-local gate_ac (f32), same store dataflow as
// R10's proven-cheap epilogue. gate_agg & scan_out are PURE-FMA.
// AC frag-native layout (per 256x256 tile): AC[(by*16+bx)<<16 | wave*8192 |
// i*1024 | j*256 | lane*4 | rr]; j=2p -> a, j=2p+1 -> c,
// unit = (bx*4+(wave>>1))*32 + p*16 + (lane&15).
// ws: [0,16Mi) x_f16 | [16,20Mi) W_f16 | [20Mi,+128Mi) AC f16 | +8Mi agg | +4Mi carry

#define LOG2_3 1.5849625007211562f

typedef _Float16 f16x8 __attribute__((ext_vector_type(8)));
typedef _Float16 f16x4 __attribute__((ext_vector_type(4)));
typedef _Float16 f16x2 __attribute__((ext_vector_type(2)));
typedef float f32x4 __attribute__((ext_vector_type(4)));

__device__ __forceinline__ float sigmoid_fast(float v) {
  return __fdividef(1.0f, 1.0f + __expf(-v));
}

__device__ __forceinline__ void async_copy16(void* lds, const void* gp) {
  __builtin_amdgcn_global_load_lds((__attribute__((address_space(1))) void*)gp,
                                   (__attribute__((address_space(3))) void*)lds,
                                   16, 0, 0);
}

// x -> xh (plain). Wa/Wi -> wh with PAIRED interleave:
// Wa_i -> row 2*(i&~15)+(i&15); Wi_i -> row 2*(i&~15)+16+(i&15).
__global__ __launch_bounds__(256) void cvt_all(const float* __restrict__ x,
                                               const float* __restrict__ Wa,
                                               const float* __restrict__ Wi,
                                               _Float16* __restrict__ xh,
                                               _Float16* __restrict__ wh) {
  int idx = blockIdx.x * 256 + threadIdx.x;
  const float* src;
  _Float16* dst;
  int off, doff;
  if (idx < 2097152) {
    src = x; dst = xh; off = idx; doff = idx;
  } else if (idx < 2097152 + 262144) {
    src = Wa; dst = wh; off = idx - 2097152;
    const int i = off >> 7, k4 = off & 127;
    doff = (((((i >> 4) << 5) | (i & 15))) << 7) | k4;
  } else {
    src = Wi; dst = wh; off = idx - 2359296;
    const int i = off >> 7, k4 = off & 127;
    doff = (((((i >> 4) << 5) | 16 | (i & 15))) << 7) | k4;
  }
  float4 v = ((const float4*)src)[off];
  f16x4 h;
  h[0] = (_Float16)v.x;
  h[1] = (_Float16)v.y;
  h[2] = (_Float16)v.z;
  h[3] = (_Float16)v.w;
  ((f16x4*)dst)[doff] = h;
}

__device__ __forceinline__ void gate_ac(float pa, float pi, float alpha, float& a, float& c) {
  float rg = sigmoid_fast(pa);
  a = alpha * exp2f(-LOG2_3 * rg);
  float ig = sigmoid_fast(pi);
  float m = fmaxf(1.0f - a * a, 1e-8f);
  c = (m * __frsqrt_rn(m)) * (ig * pi);  // sqrt(m) = m * rsqrt(m)
}

// GEMM 256x256 tile, 8 waves, K-loop identical to R9/R10 (2-phase, XOR swizzle).
// Epilogue: lane-local pairs acc[i][2p](pa) / acc[i][2p+1](pi) -> gate_ac in
// f32 -> f16x4 stores of a (j=2p) and c (j=2p+1). No shfl, no LDS, no barriers.
__global__ __launch_bounds__(512) void gemm_ac(const _Float16* __restrict__ Ah,
                                               const _Float16* __restrict__ Wh,
                                               const float* __restrict__ ba,
                                               const float* __restrict__ bi,
                                               const float* __restrict__ gate,
                                               _Float16* __restrict__ AC) {
  constexpr int K = 512;
  __shared__ __align__(16) _Float16 smem[32768];  // 64 KiB: 2 x 32KB K-buffers
  const int t = threadIdx.x;
  const int bx = blockIdx.x;  // 0..15 (n)
  const int by = blockIdx.y;  // 0..63 (m)
  const int mBase = by * 256;
  const int nBase = bx * 256;
  const int r = t >> 2;                      // staged row 0..127 (+128 for 2nd)
  const int p4 = t & 3;                      // physical 16B slot
  const int lsw = p4 ^ ((r >> 1) & 3);       // pre-swizzled source slot
  const _Float16* gA0 = Ah + (size_t)(mBase + r) * K + lsw * 8;
  const _Float16* gB0 = Wh + (size_t)(nBase + r) * K + lsw * 8;
  const int ldst = r * 32 + p4 * 8;          // byte off == t*16 (linear)

  const int lane = t & 63;
  const int wave = t >> 6;                   // 0..7
  const int wm = (wave & 1) * 128;
  const int lrow = lane & 15;
  const int quad = lane >> 4;
  const int xq = quad ^ ((lrow >> 1) & 3);   // read-side swizzle
  const int wn = (wave >> 1) * 64;

  f32x4 acc[8][4];
#pragma unroll
  for (int i = 0; i < 8; ++i)
#pragma unroll
    for (int j = 0; j < 4; ++j)
      acc[i][j] = (f32x4)0.0f;

  _Float16* b0 = smem;
  _Float16* b1 = smem + 16384;

  auto STAGE = [&](int tt, _Float16* bb) {
    const int ko = tt * 32;
    async_copy16(bb + ldst, gA0 + ko);                            // A rows 0-127
    async_copy16(bb + 4096 + ldst, gA0 + (size_t)128 * K + ko);   // A rows 128-255
    async_copy16(bb + 8192 + ldst, gB0 + ko);                     // B rows 0-127
    async_copy16(bb + 12288 + ldst, gB0 + (size_t)128 * K + ko);  // B rows 128-255
  };

  STAGE(0, b0);
  __syncthreads();

#pragma unroll
  for (int kt = 0; kt < 16; ++kt) {
    _Float16* cur = (kt & 1) ? b1 : b0;
    _Float16* nxt = (kt & 1) ? b0 : b1;
    if (kt < 15) STAGE(kt + 1, nxt);  // issue BEFORE compute; lands by next barrier
    f16x8 af[8], bf[4];
#pragma unroll
    for (int i = 0; i < 8; ++i)
      af[i] = *(const f16x8*)(cur + (wm + i * 16 + lrow) * 32 + xq * 8);
#pragma unroll
    for (int j = 0; j < 4; ++j)
      bf[j] = *(const f16x8*)(cur + 8192 + (wn + j * 16 + lrow) * 32 + xq * 8);
#pragma unroll
    for (int i = 0; i < 8; ++i)
#pragma unroll
      for (int j = 0; j < 4; ++j)
        acc[i][j] = __builtin_amdgcn_mfma_f32_16x16x32_f16(af[i], bf[j], acc[i][j], 0, 0, 0);
    __syncthreads();  // single barrier/K-step
  }

  // per-pair unit u = G*32 + p*16 + lrow, G = 64-col group
  const int G = bx * 4 + (wave >> 1);
  float bav[2], biv[2], alphav[2];
#pragma unroll
  for (int p = 0; p < 2; ++p) {
    const int u = G * 32 + p * 16 + lrow;
    bav[p] = ba[u];
    biv[p] = bi[u];
    alphav[p] = sigmoid_fast(gate[u]);
  }

  // lane-local gate epilogue: a -> j=2p, c -> j=2p+1 (frag-native f16x4).
  _Float16* pp = AC + (((size_t)by * 16 + bx) << 16) + wave * 8192 + lane * 4;
#pragma unroll
  for (int i = 0; i < 8; ++i)
#pragma unroll
    for (int p = 0; p < 2; ++p) {
      f16x4 sa, sc;
#pragma unroll
      for (int rr = 0; rr < 4; ++rr) {
        float pa = acc[i][2 * p][rr] + bav[p];
        float pi = acc[i][2 * p + 1][rr] + biv[p];
        float a, c;
        gate_ac(pa, pi, alphav[p], a, c);
        sa[rr] = (_Float16)a;
        sc[rr] = (_Float16)c;
      }
      *(f16x4*)(pp + i * 1024 + (2 * p) * 256) = sa;
      *(f16x4*)(pp + i * 1024 + (2 * p + 1) * 256) = sc;
    }
}

// AC -> 32-step chunk aggregates (A = prod a, H = fold a*H+c). PURE FMA.
// Thread = unit tt; a at j=2p, c at j=2p+1, both in lane (quad,lrow).
__global__ __launch_bounds__(256) void gate_agg(const _Float16* __restrict__ AC,
                                                float2* __restrict__ agg) {
  const int tt = blockIdx.x * 256 + threadIdx.x;  // unit 0..2047
  const int ch = blockIdx.y;                      // 0..63
  const int b = blockIdx.z;                       // 0..7
  const int G = tt >> 5;
  const int bx = G >> 2;
  const int wn_idx = G & 3;
  const int within = tt & 31;
  const int p = within >> 4;
  const int lrow = within & 15;
  const int by = b * 8 + (ch >> 3);
  const int c8 = ch & 7;
  const int wm_bit = c8 >> 2;
  const _Float16* base = AC + (((size_t)by * 16 + bx) << 16) +
                         (wm_bit + 2 * wn_idx) * 8192 + (2 * p) * 256 + lrow * 4;
  float A = 1.0f, H = 0.0f;
#pragma unroll
  for (int u = 0; u < 8; ++u) {
    const int i = ((c8 & 3) << 1) + (u >> 2);  // s = (u>>2)*16 + (u&3)*4 + rr
    const _Float16* q = base + i * 1024 + (u & 3) * 64;
    f16x4 va = *(const f16x4*)q;
    f16x4 vc = *(const f16x4*)(q + 256);
#pragma unroll
    for (int rr = 0; rr < 4; ++rr) {
      float a = (float)va[rr];
      A *= a;
      H = fmaf(a, H, (float)vc[rr]);
    }
  }
  agg[((size_t)(b * 64 + ch)) * 2048 + tt] = make_float2(A, H);
}

__global__ __launch_bounds__(64) void scan_pass2(const float2* __restrict__ agg,
                                                 float* __restrict__ carry) {
  const int i = blockIdx.x * 64 + threadIdx.x;  // grid.x=32 -> 0..2047
  const int b = blockIdx.y;
  float h = 0.0f;
  for (int c8 = 0; c8 < 8; ++c8) {
    float2 aH[8];
#pragma unroll
    for (int u = 0; u < 8; ++u)
      aH[u] = agg[((size_t)(b * 64 + c8 * 8 + u)) * 2048 + i];
#pragma unroll
    for (int u = 0; u < 8; ++u) {
      carry[((size_t)(b * 64 + c8 * 8 + u)) * 2048 + i] = h;
      h = fmaf(aH[u].x, h, aH[u].y);
    }
  }
}

// Pure fma replay from AC: h = a*h + c. Same f16 (a,c) as gate_agg consumed.
__global__ __launch_bounds__(256) void scan_out(const _Float16* __restrict__ AC,
                                                const float* __restrict__ carry,
                                                float* __restrict__ out) {
  const int tt = blockIdx.x * 256 + threadIdx.x;  // unit 0..2047
  const int ch = blockIdx.y;                      // 0..63
  const int b = blockIdx.z;                       // 0..7
  float h = carry[((size_t)(b * 64 + ch)) * 2048 + tt];
  const int G = tt >> 5;
  const int bx = G >> 2;
  const int wn_idx = G & 3;
  const int within = tt & 31;
  const int p = within >> 4;
  const int lrow = within & 15;
  const int by = b * 8 + (ch >> 3);
  const int c8 = ch & 7;
  const int wm_bit = c8 >> 2;
  const _Float16* base = AC + (((size_t)by * 16 + bx) << 16) +
                         (wm_bit + 2 * wn_idx) * 8192 + (2 * p) * 256 + lrow * 4;
  float* orow = out + ((size_t)(b * 2048 + ch * 32)) * 2048 + tt;
#pragma unroll
  for (int u = 0; u < 8; ++u) {
    const int i = ((c8 & 3) << 1) + (u >> 2);
    const _Float16* q = base + i * 1024 + (u & 3) * 64;
    f16x4 va = *(const f16x4*)q;
    f16x4 vc = *(const f16x4*)(q + 256);
#pragma unroll
    for (int rr = 0; rr < 4; ++rr) {
      h = fmaf((float)va[rr], h, (float)vc[rr]);
      __builtin_nontemporal_store(h, orow);
      orow += 2048;
    }
  }
}

extern "C" void kernel_launch(void* const* d_in, const int* in_sizes, int n_in,
                              void* d_out, int out_size, void* d_ws, size_t ws_size,
                              hipStream_t stream) {
  const float* x = (const float*)d_in[0];
  const float* Wa = (const float*)d_in[1];
  const float* ba = (const float*)d_in[2];
  const float* Wi = (const float*)d_in[3];
  const float* bi = (const float*)d_in[4];
  const float* gate = (const float*)d_in[5];
  float* out = (float*)d_out;

  char* ws = (char*)d_ws;
  _Float16* xh = (_Float16*)ws;               // 16 MiB
  _Float16* wh = (_Float16*)(ws + 16777216);  // 4 MiB (paired Wa/Wi)
  const size_t MN2 = (size_t)16384 * 4096;
  _Float16* AC = (_Float16*)(ws + 20971520);  // 128 MiB (a,c) frag-native
  float2* agg = (float2*)(ws + 20971520 + MN2 * 2);            // 8 MiB
  float* carry = (float*)(ws + 20971520 + MN2 * 2 + 8388608);  // 4 MiB

  cvt_all<<<10240, 256, 0, stream>>>(x, Wa, Wi, xh, wh);
  gemm_ac<<<dim3(16, 64), 512, 0, stream>>>(xh, wh, ba, bi, gate, AC);
  gate_agg<<<dim3(8, 64, 8), 256, 0, stream>>>(AC, agg);
  scan_pass2<<<dim3(32, 8), 64, 0, stream>>>(agg, carry);
  scan_out<<<dim3(8, 64, 8), 256, 0, stream>>>(AC, carry, out);
}